// Round 10
// baseline (284.045 us; speedup 1.0000x reference)
//
#include <hip/hip_runtime.h>
#include <hip/hip_cooperative_groups.h>

namespace cg = cooperative_groups;

#define F_DIM 256
#define H 5
#define C 7
#define PAD 8

#define PART_SH 9
#define PART_NODES 512
#define PCAP 20480
#define TILE 4096
#define EPT 4            // TILE / 1024
#define NPMAX 256
#define CSR_ROUNDS 20    // PCAP / 1024
#define NBLK 256
#define NTHR 1024

// Gather-aggregate (CSR) + fused epilogue, grid-stride form. 4 lanes/node.
template<int OUTD, int OSTRIDE, bool ADD_B3, bool GDIS, bool SCALE_OUT>
__device__ __forceinline__ void layer_work(
        const int* __restrict__ sorted, const int2* __restrict__ rpd,
        const float* __restrict__ dis, const float* __restrict__ hin,
        const float* __restrict__ bn, const float* __restrict__ Wnext,
        const float* __restrict__ b3, float* __restrict__ outp, int n,
        int gtid, int gsz) {
    for (int id = gtid; id < 4 * n; id += gsz) {
        int node = id >> 2, sub = id & 3;
        int2 rd = rpd[node];
        int deg = rd.y;
        const int* bp = sorted + rd.x;

        float acc[H] = {0.f, 0.f, 0.f, 0.f, 0.f};
        int j = sub;
        for (; j + 16 <= deg; j += 16) {
            int s0 = bp[j], s1 = bp[j + 4], s2 = bp[j + 8], s3 = bp[j + 12];
            const float4* h0 = (const float4*)(hin + (size_t)s0 * PAD);
            const float4* h1 = (const float4*)(hin + (size_t)s1 * PAD);
            const float4* h2 = (const float4*)(hin + (size_t)s2 * PAD);
            const float4* h3 = (const float4*)(hin + (size_t)s3 * PAD);
            float4 a0 = h0[0], e0 = h0[1], a1 = h1[0], e1 = h1[1];
            float4 a2 = h2[0], e2 = h2[1], a3 = h3[0], e3 = h3[1];
            if (GDIS) {
                float d0 = dis[s0], d1 = dis[s1], d2 = dis[s2], d3 = dis[s3];
                acc[0] += a0.x * d0 + a1.x * d1 + a2.x * d2 + a3.x * d3;
                acc[1] += a0.y * d0 + a1.y * d1 + a2.y * d2 + a3.y * d3;
                acc[2] += a0.z * d0 + a1.z * d1 + a2.z * d2 + a3.z * d3;
                acc[3] += a0.w * d0 + a1.w * d1 + a2.w * d2 + a3.w * d3;
                acc[4] += e0.x * d0 + e1.x * d1 + e2.x * d2 + e3.x * d3;
            } else {
                acc[0] += a0.x + a1.x + a2.x + a3.x;
                acc[1] += a0.y + a1.y + a2.y + a3.y;
                acc[2] += a0.z + a1.z + a2.z + a3.z;
                acc[3] += a0.w + a1.w + a2.w + a3.w;
                acc[4] += e0.x + e1.x + e2.x + e3.x;
            }
        }
        for (; j + 8 <= deg; j += 8) {
            int s0 = bp[j], s1 = bp[j + 4];
            const float4* h0 = (const float4*)(hin + (size_t)s0 * PAD);
            const float4* h1 = (const float4*)(hin + (size_t)s1 * PAD);
            float4 a0 = h0[0], e0 = h0[1], a1 = h1[0], e1 = h1[1];
            if (GDIS) {
                float d0 = dis[s0], d1 = dis[s1];
                acc[0] += a0.x * d0 + a1.x * d1;
                acc[1] += a0.y * d0 + a1.y * d1;
                acc[2] += a0.z * d0 + a1.z * d1;
                acc[3] += a0.w * d0 + a1.w * d1;
                acc[4] += e0.x * d0 + e1.x * d1;
            } else {
                acc[0] += a0.x + a1.x;
                acc[1] += a0.y + a1.y;
                acc[2] += a0.z + a1.z;
                acc[3] += a0.w + a1.w;
                acc[4] += e0.x + e1.x;
            }
        }
        for (; j < deg; j += 4) {
            int s0 = bp[j];
            const float4* h0 = (const float4*)(hin + (size_t)s0 * PAD);
            float4 a0 = h0[0], e0 = h0[1];
            if (GDIS) {
                float d0 = dis[s0];
                acc[0] += a0.x * d0;
                acc[1] += a0.y * d0;
                acc[2] += a0.z * d0;
                acc[3] += a0.w * d0;
                acc[4] += e0.x * d0;
            } else {
                acc[0] += a0.x;
                acc[1] += a0.y;
                acc[2] += a0.z;
                acc[3] += a0.w;
                acc[4] += e0.x;
            }
        }
#pragma unroll
        for (int c = 0; c < H; ++c) {
            acc[c] += __shfl_xor(acc[c], 1, 64);
            acc[c] += __shfl_xor(acc[c], 2, 64);
        }
        if (sub == 0) {
            float di = dis[node];
            const float4* hp4 = (const float4*)(hin + (size_t)node * PAD);
            float4 ha = hp4[0];
            float h4 = hin[(size_t)node * PAD + 4];
            float hself[H] = {ha.x, ha.y, ha.z, ha.w, h4};
            float selfs = GDIS ? di * di : di;
            float tt[H];
#pragma unroll
            for (int c = 0; c < H; ++c) {
                float v = acc[c] * di + hself[c] * selfs + bn[c];
                tt[c] = v > 0.f ? v : 0.f;
            }
            float* op = outp + (size_t)node * OSTRIDE;
#pragma unroll
            for (int c2 = 0; c2 < OUTD; ++c2) {
                float a = ADD_B3 ? b3[c2] : 0.f;
#pragma unroll
                for (int c = 0; c < H; ++c) a += tt[c] * Wnext[c * OUTD + c2];
                op[c2] = SCALE_OUT ? a * di : a;
            }
        }
    }
}

// One cooperative kernel: zero -> {partition || x@W1} -> CSR -> layer1 -> layer2,
// phases separated by grid.sync() (eliminates 5 launch boundaries at ~12us each).
__global__ __launch_bounds__(NTHR) void k_fused(
        const int* __restrict__ src, const int* __restrict__ dst,
        int* __restrict__ gcur, unsigned int* __restrict__ parr, int E,
        const float* __restrict__ x, const float* __restrict__ W1,
        float* __restrict__ hw1,
        int* __restrict__ sorted, int2* __restrict__ rpd, float* __restrict__ dis,
        const float* __restrict__ b1, const float* __restrict__ W2,
        float* __restrict__ hw2,
        const float* __restrict__ b2, const float* __restrict__ W3,
        const float* __restrict__ b3, float* __restrict__ outp,
        int n, int np) {
    cg::grid_group grid = cg::this_grid();
    __shared__ unsigned int s_out[TILE];        // 16 KB
    __shared__ unsigned char s_op[TILE];        // 4 KB
    __shared__ int s_wcur[16][NPMAX];           // 16 KB
    __shared__ int s_hist[PART_NODES];          // 2 KB (part uses [0,256))
    __shared__ int s_excl[PART_NODES];          // 2 KB
    __shared__ int s_gbase[NPMAX];              // 1 KB

    const int t = threadIdx.x;
    const int w = t >> 6;
    const int bid = blockIdx.x;
    const int nb = gridDim.x;

    // ---- phase 0: zero global cursors ----
    if (bid == 0 && t < NPMAX) gcur[t] = 0;
    grid.sync();

    // ---- phase A: edge partition (grid-stride tiles) ----
    const int nbp = (E + TILE - 1) / TILE;
    for (int tile = bid; tile < nbp; tile += nb) {
        const int t0 = tile * TILE;
        for (int i = t; i < 16 * NPMAX; i += NTHR) ((int*)s_wcur)[i] = 0;
        __syncthreads();
        unsigned int pair[EPT];
        int pp[EPT], rk[EPT];
#pragma unroll
        for (int k = 0; k < EPT; ++k) {
            int e = t0 + k * NTHR + t;
            if (e < E) {
                int d = dst[e];
                int s = src[e];
                int p = d >> PART_SH;
                pair[k] = ((unsigned)s << PART_SH) | (unsigned)(d & (PART_NODES - 1));
                pp[k] = p;
                rk[k] = atomicAdd(&s_wcur[w][p], 1);
            } else {
                pp[k] = -1;
            }
        }
        __syncthreads();
        if (t < NPMAX) {
            int sum = 0;
#pragma unroll
            for (int ww = 0; ww < 16; ++ww) sum += s_wcur[ww][t];
            s_hist[t] = sum;
        }
        __syncthreads();
        if (t < 64) {
            int base = t * 4;
            int loc[4]; int tot = 0;
#pragma unroll
            for (int k = 0; k < 4; ++k) { loc[k] = tot; tot += s_hist[base + k]; }
            int incl = tot;
#pragma unroll
            for (int off = 1; off < 64; off <<= 1) {
                int u = __shfl_up(incl, off, 64);
                if (t >= off) incl += u;
            }
            int excl = incl - tot;
#pragma unroll
            for (int k = 0; k < 4; ++k) s_excl[base + k] = excl + loc[k];
        }
        __syncthreads();
        if (t < NPMAX) {
            int run = s_excl[t];
#pragma unroll
            for (int ww = 0; ww < 16; ++ww) { int c = s_wcur[ww][t]; s_wcur[ww][t] = run; run += c; }
            int cnt = s_hist[t];
            s_gbase[t] = (cnt > 0) ? atomicAdd(&gcur[t], cnt) : 0;
        }
        __syncthreads();
#pragma unroll
        for (int k = 0; k < EPT; ++k) {
            if (pp[k] >= 0) {
                int pos = s_wcur[w][pp[k]] + rk[k];
                s_out[pos] = pair[k];
                s_op[pos] = (unsigned char)pp[k];
            }
        }
        __syncthreads();
        const int tilecnt = s_excl[NPMAX - 1] + s_hist[NPMAX - 1];
#pragma unroll
        for (int k = 0; k < EPT; ++k) {
            int i = k * NTHR + t;
            if (i < tilecnt) {
                int p = s_op[i];
                int gpos = s_gbase[p] + (i - s_excl[p]);
                if (gpos < PCAP)
                    parr[(size_t)p * PCAP + gpos] = s_out[i];
            }
        }
        __syncthreads();
    }

    // ---- phase A (cont.): hw1 = x @ W1, one wave per row ----
    {
        const int lane = t & 63;
        const int gw = bid * 16 + w;
        const int nw = nb * 16;
        float w4[4][H];
#pragma unroll
        for (int j = 0; j < 4; ++j)
#pragma unroll
            for (int c = 0; c < H; ++c)
                w4[j][c] = W1[(4 * lane + j) * H + c];
        for (int row = gw; row < n; row += nw) {
            float4 xv = *reinterpret_cast<const float4*>(x + (size_t)row * F_DIM + 4 * lane);
            float pr[H];
#pragma unroll
            for (int c = 0; c < H; ++c)
                pr[c] = xv.x * w4[0][c] + xv.y * w4[1][c] + xv.z * w4[2][c] + xv.w * w4[3][c];
#pragma unroll
            for (int off = 32; off >= 1; off >>= 1)
#pragma unroll
                for (int c = 0; c < H; ++c)
                    pr[c] += __shfl_xor(pr[c], off, 64);
            if (lane == 0) {
                float* o = hw1 + (size_t)row * PAD;
                *reinterpret_cast<float4*>(o) = make_float4(pr[0], pr[1], pr[2], pr[3]);
                o[4] = pr[4];
            }
        }
    }
    grid.sync();

    // ---- phase B: per-partition CSR build (register-cached two-pass) ----
    for (int p = bid; p < np; p += nb) {
        int m = gcur[p]; if (m > PCAP) m = PCAP;
        const unsigned int* pp_ = parr + (size_t)p * PCAP;
        if (t < PART_NODES) s_hist[t] = 0;
        __syncthreads();
        unsigned int pr[CSR_ROUNDS];
        int rk2[CSR_ROUNDS];
#pragma unroll
        for (int k = 0; k < CSR_ROUNDS; ++k) {
            int i = k * NTHR + t;
            if (i < m) {
                pr[k] = pp_[i];
                rk2[k] = atomicAdd(&s_hist[pr[k] & (PART_NODES - 1)], 1);
            }
        }
        __syncthreads();
        if (t < 64) {
            int base = t * 8;
            int loc[8]; int tot = 0;
#pragma unroll
            for (int k = 0; k < 8; ++k) { loc[k] = tot; tot += s_hist[base + k]; }
            int incl = tot;
#pragma unroll
            for (int off = 1; off < 64; off <<= 1) {
                int u = __shfl_up(incl, off, 64);
                if (t >= off) incl += u;
            }
            int excl = incl - tot;
#pragma unroll
            for (int k = 0; k < 8; ++k) s_excl[base + k] = excl + loc[k];
        }
        __syncthreads();
        if (t < PART_NODES) {
            int node = p * PART_NODES + t;
            if (node < n) {
                int dg = s_hist[t];
                rpd[node] = make_int2(p * PCAP + s_excl[t], dg);
                dis[node] = rsqrtf((float)dg + 1.0f);
            }
        }
#pragma unroll
        for (int k = 0; k < CSR_ROUNDS; ++k) {
            int i = k * NTHR + t;
            if (i < m) {
                int dloc = pr[k] & (PART_NODES - 1);
                sorted[(size_t)p * PCAP + s_excl[dloc] + rk2[k]] = (int)(pr[k] >> PART_SH);
            }
        }
        __syncthreads();
    }
    grid.sync();

    // ---- phase C: layer1 (raw h, gather dis[src]; out = (t@W2)*dis[node]) ----
    const int gtid = bid * NTHR + t;
    const int gsz = nb * NTHR;
    layer_work<H, PAD, false, true, true>(sorted, rpd, dis, hw1, b1, W2, nullptr, hw2, n, gtid, gsz);
    grid.sync();

    // ---- phase D: layer2 (hw2 carries dis factor; logits + b3) ----
    layer_work<C, C, true, false, false>(sorted, rpd, dis, hw2, b2, W3, b3, outp, n, gtid, gsz);
}

extern "C" void kernel_launch(void* const* d_in, const int* in_sizes, int n_in,
                              void* d_out, int out_size, void* d_ws, size_t ws_size,
                              hipStream_t stream) {
    const float* x  = (const float*)d_in[0];
    const int*   ei = (const int*)d_in[1];
    const float* W1 = (const float*)d_in[2];
    const float* b1 = (const float*)d_in[3];
    const float* W2 = (const float*)d_in[4];
    const float* b2 = (const float*)d_in[5];
    const float* W3 = (const float*)d_in[6];
    const float* b3 = (const float*)d_in[7];
    float* out = (float*)d_out;

    const int n = in_sizes[0] / F_DIM;
    const int E = in_sizes[1] / 2;
    const int* src = ei;
    const int* dst = ei + E;
    const int np = (n + PART_NODES - 1) / PART_NODES;

    char* ws = (char*)d_ws;
    size_t off = 0;
    int* gcur = (int*)(ws + off);                   off += NPMAX * 4;
    unsigned int* parr = (unsigned int*)(ws + off); off += (size_t)np * PCAP * 4;
    int* sorted = (int*)(ws + off);                 off += (size_t)np * PCAP * 4;
    int2* rpd = (int2*)(ws + off);                  off += (size_t)n * 8;
    float* dis = (float*)(ws + off);                off += (size_t)n * 4;
    float* hw1 = (float*)(ws + off);                off += (size_t)n * PAD * 4;
    float* hw2 = (float*)(ws + off);                off += (size_t)n * PAD * 4;

    void* args[] = {
        (void*)&src, (void*)&dst, (void*)&gcur, (void*)&parr, (void*)&E,
        (void*)&x, (void*)&W1, (void*)&hw1,
        (void*)&sorted, (void*)&rpd, (void*)&dis,
        (void*)&b1, (void*)&W2, (void*)&hw2,
        (void*)&b2, (void*)&W3, (void*)&b3, (void*)&out,
        (void*)&n, (void*)&np
    };
    hipLaunchCooperativeKernel((const void*)k_fused, dim3(NBLK), dim3(NTHR),
                               args, 0, stream);
}

// Round 11
// 171.188 us; speedup vs baseline: 1.6593x; 1.6593x over previous
//
#include <hip/hip_runtime.h>

#define F_DIM 256
#define H 5
#define C 7
#define PAD 8

#define PART_SH 9
#define PART_NODES 512
#define PCAP 20480
#define TILE 2048
#define NPMAX 256
#define CSR_ROUNDS 20   // PCAP / 1024

// hw1 = x @ W1 (one wave per row); block 0 also zeroes the partition cursors
// (stream ordering guarantees completion before k_part).
__global__ __launch_bounds__(256) void k_xw1z(const float* __restrict__ x,
                                              const float* __restrict__ W1,
                                              float* __restrict__ hw1,
                                              int* __restrict__ gcur, int n) {
    if (blockIdx.x == 0 && threadIdx.x < NPMAX) gcur[threadIdx.x] = 0;
    const int lane = threadIdx.x & 63;
    const int wid = (blockIdx.x * blockDim.x + threadIdx.x) >> 6;
    const int nw = (gridDim.x * blockDim.x) >> 6;
    float w4[4][H];
#pragma unroll
    for (int j = 0; j < 4; ++j)
#pragma unroll
        for (int c = 0; c < H; ++c)
            w4[j][c] = W1[(4 * lane + j) * H + c];
    for (int row = wid; row < n; row += nw) {
        float4 xv = *reinterpret_cast<const float4*>(x + (size_t)row * F_DIM + 4 * lane);
        float pr[H];
#pragma unroll
        for (int c = 0; c < H; ++c)
            pr[c] = xv.x * w4[0][c] + xv.y * w4[1][c] + xv.z * w4[2][c] + xv.w * w4[3][c];
#pragma unroll
        for (int off = 32; off >= 1; off >>= 1)
#pragma unroll
            for (int c = 0; c < H; ++c)
                pr[c] += __shfl_xor(pr[c], off, 64);
        if (lane == 0) {
            float* o = hw1 + (size_t)row * PAD;
            *reinterpret_cast<float4*>(o) = make_float4(pr[0], pr[1], pr[2], pr[3]);
            o[4] = pr[4];
        }
    }
}

// Partition edges by dst>>9 (R4's proven 512-thread version: wave-private
// histograms, single-wave shuffle scan, per-wave cursors, coalesced flush).
__global__ __launch_bounds__(512) void k_part(const int* __restrict__ src,
                                              const int* __restrict__ dst,
                                              int* __restrict__ gcur,
                                              unsigned int* __restrict__ parr, int E) {
    __shared__ unsigned int s_pair[TILE];
    __shared__ unsigned char s_pp[TILE];
    __shared__ unsigned int s_out[TILE];
    __shared__ unsigned char s_op[TILE];
    __shared__ int s_wcur[8][NPMAX];
    __shared__ int s_hist[NPMAX];
    __shared__ int s_excl[NPMAX];
    __shared__ int s_gbase[NPMAX];

    const int t = threadIdx.x;
    const int w = t >> 6;
    const int t0 = blockIdx.x * TILE;

    for (int i = t; i < 8 * NPMAX; i += 512) ((int*)s_wcur)[i] = 0;
    __syncthreads();

#pragma unroll
    for (int k = 0; k < 4; ++k) {
        int i = k * 512 + t;
        int e = t0 + i;
        if (e < E) {
            int d = dst[e];
            int s = src[e];
            int p = d >> PART_SH;
            s_pair[i] = ((unsigned)s << PART_SH) | (unsigned)(d & (PART_NODES - 1));
            s_pp[i] = (unsigned char)p;
            atomicAdd(&s_wcur[w][p], 1);
        } else {
            s_pp[i] = 0;
        }
    }
    __syncthreads();
    if (t < NPMAX) {
        int sum = 0;
#pragma unroll
        for (int ww = 0; ww < 8; ++ww) sum += s_wcur[ww][t];
        s_hist[t] = sum;
    }
    __syncthreads();
    if (t < 64) {
        int base = t * 4;
        int loc[4]; int tot = 0;
#pragma unroll
        for (int k = 0; k < 4; ++k) { loc[k] = tot; tot += s_hist[base + k]; }
        int incl = tot;
#pragma unroll
        for (int off = 1; off < 64; off <<= 1) {
            int u = __shfl_up(incl, off, 64);
            if (t >= off) incl += u;
        }
        int excl = incl - tot;
#pragma unroll
        for (int k = 0; k < 4; ++k) s_excl[base + k] = excl + loc[k];
    }
    __syncthreads();
    if (t < NPMAX) {
        int run = s_excl[t];
#pragma unroll
        for (int ww = 0; ww < 8; ++ww) { int c = s_wcur[ww][t]; s_wcur[ww][t] = run; run += c; }
        int cnt = s_hist[t];
        s_gbase[t] = (cnt > 0) ? atomicAdd(&gcur[t], cnt) : 0;
    }
    __syncthreads();
#pragma unroll
    for (int k = 0; k < 4; ++k) {
        int i = k * 512 + t;
        int e = t0 + i;
        if (e < E) {
            int p = s_pp[i];
            int pos = atomicAdd(&s_wcur[w][p], 1);
            s_out[pos] = s_pair[i];
            s_op[pos] = (unsigned char)p;
        }
    }
    __syncthreads();
    const int tilecnt = s_excl[NPMAX - 1] + s_hist[NPMAX - 1];
#pragma unroll
    for (int k = 0; k < 4; ++k) {
        int i = k * 512 + t;
        if (i < tilecnt) {
            int p = s_op[i];
            int gpos = s_gbase[p] + (i - s_excl[p]);
            if (gpos < PCAP)
                parr[(size_t)p * PCAP + gpos] = s_out[i];
        }
    }
}

// Per-partition CSR build, 1024 threads, register-cached two-pass
// (parr read once; ranks from a single LDS-atomic pass).
__global__ __launch_bounds__(1024) void k_csr(
        const int* __restrict__ gcur, const unsigned int* __restrict__ parr,
        int* __restrict__ sorted, int2* __restrict__ rpd, float* __restrict__ dis, int n) {
    __shared__ int s_cnt[PART_NODES];
    __shared__ int s_excl[PART_NODES];
    const int p = blockIdx.x;
    const int t = threadIdx.x;
    int m = gcur[p]; if (m > PCAP) m = PCAP;
    const unsigned int* pp = parr + (size_t)p * PCAP;

    if (t < PART_NODES) s_cnt[t] = 0;
    __syncthreads();

    unsigned int pr[CSR_ROUNDS];
    int rk[CSR_ROUNDS];
#pragma unroll
    for (int k = 0; k < CSR_ROUNDS; ++k) {
        int i = k * 1024 + t;
        if (i < m) {
            pr[k] = pp[i];
            rk[k] = atomicAdd(&s_cnt[pr[k] & (PART_NODES - 1)], 1);
        }
    }
    __syncthreads();
    if (t < 64) {
        int base = t * 8;
        int loc[8]; int tot = 0;
#pragma unroll
        for (int k = 0; k < 8; ++k) { loc[k] = tot; tot += s_cnt[base + k]; }
        int incl = tot;
#pragma unroll
        for (int off = 1; off < 64; off <<= 1) {
            int u = __shfl_up(incl, off, 64);
            if (t >= off) incl += u;
        }
        int excl = incl - tot;
#pragma unroll
        for (int k = 0; k < 8; ++k) s_excl[base + k] = excl + loc[k];
    }
    __syncthreads();
    if (t < PART_NODES) {
        int node = p * PART_NODES + t;
        if (node < n) {
            int dg = s_cnt[t];
            rpd[node] = make_int2(p * PCAP + s_excl[t], dg);
            dis[node] = rsqrtf((float)dg + 1.0f);
        }
    }
#pragma unroll
    for (int k = 0; k < CSR_ROUNDS; ++k) {
        int i = k * 1024 + t;
        if (i < m) {
            int dloc = pr[k] & (PART_NODES - 1);
            sorted[(size_t)p * PCAP + s_excl[dloc] + rk[k]] = (int)(pr[k] >> PART_SH);
        }
    }
}

// Gather-aggregate (CSR) + fused epilogue. 4 lanes per node, 4-deep gather ILP.
template<int OUTD, int OSTRIDE, bool ADD_B3, bool GDIS, bool SCALE_OUT>
__global__ __launch_bounds__(256) void k_layer(
        const int* __restrict__ sorted, const int2* __restrict__ rpd,
        const float* __restrict__ dis,
        const float* __restrict__ hin, const float* __restrict__ bn,
        const float* __restrict__ Wnext, const float* __restrict__ b3,
        float* __restrict__ outp, int n) {
    int tid = blockIdx.x * blockDim.x + threadIdx.x;
    int node = tid >> 2, sub = tid & 3;
    if (node >= n) return;
    int2 rd = rpd[node];
    int deg = rd.y;
    const int* bp = sorted + rd.x;

    float acc[H] = {0.f, 0.f, 0.f, 0.f, 0.f};
    int j = sub;
    for (; j + 16 <= deg; j += 16) {
        int s0 = bp[j], s1 = bp[j + 4], s2 = bp[j + 8], s3 = bp[j + 12];
        const float4* h0 = (const float4*)(hin + (size_t)s0 * PAD);
        const float4* h1 = (const float4*)(hin + (size_t)s1 * PAD);
        const float4* h2 = (const float4*)(hin + (size_t)s2 * PAD);
        const float4* h3 = (const float4*)(hin + (size_t)s3 * PAD);
        float4 a0 = h0[0], e0 = h0[1], a1 = h1[0], e1 = h1[1];
        float4 a2 = h2[0], e2 = h2[1], a3 = h3[0], e3 = h3[1];
        if (GDIS) {
            float d0 = dis[s0], d1 = dis[s1], d2 = dis[s2], d3 = dis[s3];
            acc[0] += a0.x * d0 + a1.x * d1 + a2.x * d2 + a3.x * d3;
            acc[1] += a0.y * d0 + a1.y * d1 + a2.y * d2 + a3.y * d3;
            acc[2] += a0.z * d0 + a1.z * d1 + a2.z * d2 + a3.z * d3;
            acc[3] += a0.w * d0 + a1.w * d1 + a2.w * d2 + a3.w * d3;
            acc[4] += e0.x * d0 + e1.x * d1 + e2.x * d2 + e3.x * d3;
        } else {
            acc[0] += a0.x + a1.x + a2.x + a3.x;
            acc[1] += a0.y + a1.y + a2.y + a3.y;
            acc[2] += a0.z + a1.z + a2.z + a3.z;
            acc[3] += a0.w + a1.w + a2.w + a3.w;
            acc[4] += e0.x + e1.x + e2.x + e3.x;
        }
    }
    for (; j + 8 <= deg; j += 8) {
        int s0 = bp[j], s1 = bp[j + 4];
        const float4* h0 = (const float4*)(hin + (size_t)s0 * PAD);
        const float4* h1 = (const float4*)(hin + (size_t)s1 * PAD);
        float4 a0 = h0[0], e0 = h0[1], a1 = h1[0], e1 = h1[1];
        if (GDIS) {
            float d0 = dis[s0], d1 = dis[s1];
            acc[0] += a0.x * d0 + a1.x * d1;
            acc[1] += a0.y * d0 + a1.y * d1;
            acc[2] += a0.z * d0 + a1.z * d1;
            acc[3] += a0.w * d0 + a1.w * d1;
            acc[4] += e0.x * d0 + e1.x * d1;
        } else {
            acc[0] += a0.x + a1.x;
            acc[1] += a0.y + a1.y;
            acc[2] += a0.z + a1.z;
            acc[3] += a0.w + a1.w;
            acc[4] += e0.x + e1.x;
        }
    }
    for (; j < deg; j += 4) {
        int s0 = bp[j];
        const float4* h0 = (const float4*)(hin + (size_t)s0 * PAD);
        float4 a0 = h0[0], e0 = h0[1];
        if (GDIS) {
            float d0 = dis[s0];
            acc[0] += a0.x * d0;
            acc[1] += a0.y * d0;
            acc[2] += a0.z * d0;
            acc[3] += a0.w * d0;
            acc[4] += e0.x * d0;
        } else {
            acc[0] += a0.x;
            acc[1] += a0.y;
            acc[2] += a0.z;
            acc[3] += a0.w;
            acc[4] += e0.x;
        }
    }
#pragma unroll
    for (int c = 0; c < H; ++c) {
        acc[c] += __shfl_xor(acc[c], 1, 64);
        acc[c] += __shfl_xor(acc[c], 2, 64);
    }
    if (sub != 0) return;

    float di = dis[node];
    const float4* hp4 = (const float4*)(hin + (size_t)node * PAD);
    float4 ha = hp4[0];
    float h4 = hin[(size_t)node * PAD + 4];
    float hself[H] = {ha.x, ha.y, ha.z, ha.w, h4};
    float selfs = GDIS ? di * di : di;
    float tt[H];
#pragma unroll
    for (int c = 0; c < H; ++c) {
        float v = acc[c] * di + hself[c] * selfs + bn[c];
        tt[c] = v > 0.f ? v : 0.f;
    }
    float* op = outp + (size_t)node * OSTRIDE;
#pragma unroll
    for (int c2 = 0; c2 < OUTD; ++c2) {
        float a = ADD_B3 ? b3[c2] : 0.f;
#pragma unroll
        for (int c = 0; c < H; ++c) a += tt[c] * Wnext[c * OUTD + c2];
        op[c2] = SCALE_OUT ? a * di : a;
    }
}

extern "C" void kernel_launch(void* const* d_in, const int* in_sizes, int n_in,
                              void* d_out, int out_size, void* d_ws, size_t ws_size,
                              hipStream_t stream) {
    const float* x  = (const float*)d_in[0];
    const int*   ei = (const int*)d_in[1];
    const float* W1 = (const float*)d_in[2];
    const float* b1 = (const float*)d_in[3];
    const float* W2 = (const float*)d_in[4];
    const float* b2 = (const float*)d_in[5];
    const float* W3 = (const float*)d_in[6];
    const float* b3 = (const float*)d_in[7];
    float* out = (float*)d_out;

    const int n = in_sizes[0] / F_DIM;
    const int E = in_sizes[1] / 2;
    const int* src = ei;
    const int* dst = ei + E;
    const int np = (n + PART_NODES - 1) / PART_NODES;

    char* ws = (char*)d_ws;
    size_t off = 0;
    int* gcur = (int*)(ws + off);                   off += NPMAX * 4;
    unsigned int* parr = (unsigned int*)(ws + off); off += (size_t)np * PCAP * 4;
    int* sorted = (int*)(ws + off);                 off += (size_t)np * PCAP * 4;
    int2* rpd = (int2*)(ws + off);                  off += (size_t)n * 8;
    float* dis = (float*)(ws + off);                off += (size_t)n * 4;
    float* hw1 = (float*)(ws + off);                off += (size_t)n * PAD * 4;
    float* hw2 = (float*)(ws + off);                off += (size_t)n * PAD * 4;

    const int nbp = (E + TILE - 1) / TILE;
    const int nb4 = (4 * n + 255) / 256;

    k_xw1z<<<1024, 256, 0, stream>>>(x, W1, hw1, gcur, n);
    k_part<<<nbp, 512, 0, stream>>>(src, dst, gcur, parr, E);
    k_csr<<<np, 1024, 0, stream>>>(gcur, parr, sorted, rpd, dis, n);
    // layer1: raw h in hw1, gather dis[src]; write (t@W2)*dis[node] into hw2
    k_layer<H, PAD, false, true, true><<<nb4, 256, 0, stream>>>(
        sorted, rpd, dis, hw1, b1, W2, nullptr, hw2, n);
    // layer2: hw2 already carries dis factor; add b3, write logits
    k_layer<C, C, true, false, false><<<nb4, 256, 0, stream>>>(
        sorted, rpd, dis, hw2, b2, W3, b3, out, n);
}

// Round 12
// 148.128 us; speedup vs baseline: 1.9176x; 1.1557x over previous
//
#include <hip/hip_runtime.h>

#define F_DIM 256
#define H 5
#define C 7
#define PAD 8

#define PART_SH 9
#define PART_NODES 512
#define PCAP 20480
#define TILE 2048
#define NPMAX 256
#define CSR_ROUNDS 20   // PCAP / 1024

// hw1 = x @ W1, TRANSPOSED: one thread per row, 64 float4 loads of its own
// row, W1 indices lane-uniform (compiler scalarizes to s_load). No LDS, no
// shuffles. Block 0 also zeroes the partition cursors (runs before k_part).
__global__ __launch_bounds__(256) void k_xw1z(const float* __restrict__ x,
                                              const float* __restrict__ W1,
                                              float* __restrict__ hw1,
                                              int* __restrict__ gcur, int n) {
    if (blockIdx.x == 0 && threadIdx.x < NPMAX) gcur[threadIdx.x] = 0;
    int row = blockIdx.x * 256 + threadIdx.x;
    if (row >= n) return;
    const float4* xp = (const float4*)(x + (size_t)row * F_DIM);
    float acc[H] = {0.f, 0.f, 0.f, 0.f, 0.f};
#pragma unroll 8
    for (int f4 = 0; f4 < F_DIM / 4; ++f4) {
        float4 v = xp[f4];
        const float* wp = W1 + f4 * 4 * H;   // lane-uniform -> scalar loads
#pragma unroll
        for (int c = 0; c < H; ++c)
            acc[c] += v.x * wp[c] + v.y * wp[H + c] + v.z * wp[2 * H + c] + v.w * wp[3 * H + c];
    }
    float* o = hw1 + (size_t)row * PAD;
    *reinterpret_cast<float4*>(o) = make_float4(acc[0], acc[1], acc[2], acc[3]);
    o[4] = acc[4];
}

// Partition edges by dst>>9 (proven 512-thread version: wave-private
// histograms, single-wave shuffle scan, per-wave cursors, coalesced flush).
__global__ __launch_bounds__(512) void k_part(const int* __restrict__ src,
                                              const int* __restrict__ dst,
                                              int* __restrict__ gcur,
                                              unsigned int* __restrict__ parr, int E) {
    __shared__ unsigned int s_pair[TILE];
    __shared__ unsigned char s_pp[TILE];
    __shared__ unsigned int s_out[TILE];
    __shared__ unsigned char s_op[TILE];
    __shared__ int s_wcur[8][NPMAX];
    __shared__ int s_hist[NPMAX];
    __shared__ int s_excl[NPMAX];
    __shared__ int s_gbase[NPMAX];

    const int t = threadIdx.x;
    const int w = t >> 6;
    const int t0 = blockIdx.x * TILE;

    for (int i = t; i < 8 * NPMAX; i += 512) ((int*)s_wcur)[i] = 0;
    __syncthreads();

#pragma unroll
    for (int k = 0; k < 4; ++k) {
        int i = k * 512 + t;
        int e = t0 + i;
        if (e < E) {
            int d = dst[e];
            int s = src[e];
            int p = d >> PART_SH;
            s_pair[i] = ((unsigned)s << PART_SH) | (unsigned)(d & (PART_NODES - 1));
            s_pp[i] = (unsigned char)p;
            atomicAdd(&s_wcur[w][p], 1);
        } else {
            s_pp[i] = 0;
        }
    }
    __syncthreads();
    if (t < NPMAX) {
        int sum = 0;
#pragma unroll
        for (int ww = 0; ww < 8; ++ww) sum += s_wcur[ww][t];
        s_hist[t] = sum;
    }
    __syncthreads();
    if (t < 64) {
        int base = t * 4;
        int loc[4]; int tot = 0;
#pragma unroll
        for (int k = 0; k < 4; ++k) { loc[k] = tot; tot += s_hist[base + k]; }
        int incl = tot;
#pragma unroll
        for (int off = 1; off < 64; off <<= 1) {
            int u = __shfl_up(incl, off, 64);
            if (t >= off) incl += u;
        }
        int excl = incl - tot;
#pragma unroll
        for (int k = 0; k < 4; ++k) s_excl[base + k] = excl + loc[k];
    }
    __syncthreads();
    if (t < NPMAX) {
        int run = s_excl[t];
#pragma unroll
        for (int ww = 0; ww < 8; ++ww) { int c = s_wcur[ww][t]; s_wcur[ww][t] = run; run += c; }
        int cnt = s_hist[t];
        s_gbase[t] = (cnt > 0) ? atomicAdd(&gcur[t], cnt) : 0;
    }
    __syncthreads();
#pragma unroll
    for (int k = 0; k < 4; ++k) {
        int i = k * 512 + t;
        int e = t0 + i;
        if (e < E) {
            int p = s_pp[i];
            int pos = atomicAdd(&s_wcur[w][p], 1);
            s_out[pos] = s_pair[i];
            s_op[pos] = (unsigned char)p;
        }
    }
    __syncthreads();
    const int tilecnt = s_excl[NPMAX - 1] + s_hist[NPMAX - 1];
#pragma unroll
    for (int k = 0; k < 4; ++k) {
        int i = k * 512 + t;
        if (i < tilecnt) {
            int p = s_op[i];
            int gpos = s_gbase[p] + (i - s_excl[p]);
            if (gpos < PCAP)
                parr[(size_t)p * PCAP + gpos] = s_out[i];
        }
    }
}

// Per-partition CSR build (1024 threads, register-cached two-pass) + epilogue:
// dis, rpd, and hw1s = hw1 * dis[node] (removes per-edge dis gather in layer1).
__global__ __launch_bounds__(1024) void k_csr(
        const int* __restrict__ gcur, const unsigned int* __restrict__ parr,
        int* __restrict__ sorted, int2* __restrict__ rpd, float* __restrict__ dis,
        const float* __restrict__ hw1, float* __restrict__ hw1s, int n) {
    __shared__ int s_cnt[PART_NODES];
    __shared__ int s_excl[PART_NODES];
    const int p = blockIdx.x;
    const int t = threadIdx.x;
    int m = gcur[p]; if (m > PCAP) m = PCAP;
    const unsigned int* pp = parr + (size_t)p * PCAP;

    if (t < PART_NODES) s_cnt[t] = 0;
    __syncthreads();

    unsigned int pr[CSR_ROUNDS];
    int rk[CSR_ROUNDS];
#pragma unroll
    for (int k = 0; k < CSR_ROUNDS; ++k) {
        int i = k * 1024 + t;
        if (i < m) {
            pr[k] = pp[i];
            rk[k] = atomicAdd(&s_cnt[pr[k] & (PART_NODES - 1)], 1);
        }
    }
    __syncthreads();
    if (t < 64) {
        int base = t * 8;
        int loc[8]; int tot = 0;
#pragma unroll
        for (int k = 0; k < 8; ++k) { loc[k] = tot; tot += s_cnt[base + k]; }
        int incl = tot;
#pragma unroll
        for (int off = 1; off < 64; off <<= 1) {
            int u = __shfl_up(incl, off, 64);
            if (t >= off) incl += u;
        }
        int excl = incl - tot;
#pragma unroll
        for (int k = 0; k < 8; ++k) s_excl[base + k] = excl + loc[k];
    }
    __syncthreads();
    if (t < PART_NODES) {
        int node = p * PART_NODES + t;
        if (node < n) {
            int dg = s_cnt[t];
            rpd[node] = make_int2(p * PCAP + s_excl[t], dg);
            float di = rsqrtf((float)dg + 1.0f);
            dis[node] = di;
            const float* hp = hw1 + (size_t)node * PAD;
            float4 a = *(const float4*)hp;
            float h4 = hp[4];
            float* os = hw1s + (size_t)node * PAD;
            *reinterpret_cast<float4*>(os) = make_float4(a.x * di, a.y * di, a.z * di, a.w * di);
            os[4] = h4 * di;
        }
    }
#pragma unroll
    for (int k = 0; k < CSR_ROUNDS; ++k) {
        int i = k * 1024 + t;
        if (i < m) {
            int dloc = pr[k] & (PART_NODES - 1);
            sorted[(size_t)p * PCAP + s_excl[dloc] + rk[k]] = (int)(pr[k] >> PART_SH);
        }
    }
}

// Gather-aggregate (CSR) + fused epilogue. hin is pre-scaled by dis[src], so
// no per-edge dis gather. 4 lanes per node, 4-deep gather ILP.
template<int OUTD, int OSTRIDE, bool ADD_B3, bool SCALE_OUT>
__global__ __launch_bounds__(256) void k_layer(
        const int* __restrict__ sorted, const int2* __restrict__ rpd,
        const float* __restrict__ dis,
        const float* __restrict__ hin, const float* __restrict__ bn,
        const float* __restrict__ Wnext, const float* __restrict__ b3,
        float* __restrict__ outp, int n) {
    int tid = blockIdx.x * blockDim.x + threadIdx.x;
    int node = tid >> 2, sub = tid & 3;
    if (node >= n) return;
    int2 rd = rpd[node];
    int deg = rd.y;
    const int* bp = sorted + rd.x;

    float acc[H] = {0.f, 0.f, 0.f, 0.f, 0.f};
    int j = sub;
    for (; j + 16 <= deg; j += 16) {
        int s0 = bp[j], s1 = bp[j + 4], s2 = bp[j + 8], s3 = bp[j + 12];
        const float4* h0 = (const float4*)(hin + (size_t)s0 * PAD);
        const float4* h1 = (const float4*)(hin + (size_t)s1 * PAD);
        const float4* h2 = (const float4*)(hin + (size_t)s2 * PAD);
        const float4* h3 = (const float4*)(hin + (size_t)s3 * PAD);
        float4 a0 = h0[0], e0 = h0[1], a1 = h1[0], e1 = h1[1];
        float4 a2 = h2[0], e2 = h2[1], a3 = h3[0], e3 = h3[1];
        acc[0] += a0.x + a1.x + a2.x + a3.x;
        acc[1] += a0.y + a1.y + a2.y + a3.y;
        acc[2] += a0.z + a1.z + a2.z + a3.z;
        acc[3] += a0.w + a1.w + a2.w + a3.w;
        acc[4] += e0.x + e1.x + e2.x + e3.x;
    }
    for (; j + 8 <= deg; j += 8) {
        int s0 = bp[j], s1 = bp[j + 4];
        const float4* h0 = (const float4*)(hin + (size_t)s0 * PAD);
        const float4* h1 = (const float4*)(hin + (size_t)s1 * PAD);
        float4 a0 = h0[0], e0 = h0[1], a1 = h1[0], e1 = h1[1];
        acc[0] += a0.x + a1.x;
        acc[1] += a0.y + a1.y;
        acc[2] += a0.z + a1.z;
        acc[3] += a0.w + a1.w;
        acc[4] += e0.x + e1.x;
    }
    for (; j < deg; j += 4) {
        int s0 = bp[j];
        const float4* h0 = (const float4*)(hin + (size_t)s0 * PAD);
        float4 a0 = h0[0], e0 = h0[1];
        acc[0] += a0.x;
        acc[1] += a0.y;
        acc[2] += a0.z;
        acc[3] += a0.w;
        acc[4] += e0.x;
    }
#pragma unroll
    for (int c = 0; c < H; ++c) {
        acc[c] += __shfl_xor(acc[c], 1, 64);
        acc[c] += __shfl_xor(acc[c], 2, 64);
    }
    if (sub != 0) return;

    float di = dis[node];
    const float4* hp4 = (const float4*)(hin + (size_t)node * PAD);
    float4 ha = hp4[0];
    float h4 = hin[(size_t)node * PAD + 4];
    float hself[H] = {ha.x, ha.y, ha.z, ha.w, h4};
    float tt[H];
#pragma unroll
    for (int c = 0; c < H; ++c) {
        float v = (acc[c] + hself[c]) * di + bn[c];
        tt[c] = v > 0.f ? v : 0.f;
    }
    float* op = outp + (size_t)node * OSTRIDE;
#pragma unroll
    for (int c2 = 0; c2 < OUTD; ++c2) {
        float a = ADD_B3 ? b3[c2] : 0.f;
#pragma unroll
        for (int c = 0; c < H; ++c) a += tt[c] * Wnext[c * OUTD + c2];
        op[c2] = SCALE_OUT ? a * di : a;
    }
}

extern "C" void kernel_launch(void* const* d_in, const int* in_sizes, int n_in,
                              void* d_out, int out_size, void* d_ws, size_t ws_size,
                              hipStream_t stream) {
    const float* x  = (const float*)d_in[0];
    const int*   ei = (const int*)d_in[1];
    const float* W1 = (const float*)d_in[2];
    const float* b1 = (const float*)d_in[3];
    const float* W2 = (const float*)d_in[4];
    const float* b2 = (const float*)d_in[5];
    const float* W3 = (const float*)d_in[6];
    const float* b3 = (const float*)d_in[7];
    float* out = (float*)d_out;

    const int n = in_sizes[0] / F_DIM;
    const int E = in_sizes[1] / 2;
    const int* src = ei;
    const int* dst = ei + E;
    const int np = (n + PART_NODES - 1) / PART_NODES;

    char* ws = (char*)d_ws;
    size_t off = 0;
    int* gcur = (int*)(ws + off);                   off += NPMAX * 4;
    unsigned int* parr = (unsigned int*)(ws + off); off += (size_t)np * PCAP * 4;
    int* sorted = (int*)(ws + off);                 off += (size_t)np * PCAP * 4;
    int2* rpd = (int2*)(ws + off);                  off += (size_t)n * 8;
    float* dis = (float*)(ws + off);                off += (size_t)n * 4;
    float* hw1 = (float*)(ws + off);                off += (size_t)n * PAD * 4;
    float* hw1s = (float*)(ws + off);               off += (size_t)n * PAD * 4;
    float* hw2 = (float*)(ws + off);                off += (size_t)n * PAD * 4;

    const int nbp = (E + TILE - 1) / TILE;
    const int nbx = (n + 255) / 256;
    const int nb4 = (4 * n + 255) / 256;

    k_xw1z<<<nbx, 256, 0, stream>>>(x, W1, hw1, gcur, n);
    k_part<<<nbp, 512, 0, stream>>>(src, dst, gcur, parr, E);
    k_csr<<<np, 1024, 0, stream>>>(gcur, parr, sorted, rpd, dis, hw1, hw1s, n);
    // layer1: hw1s pre-scaled by dis; write (t@W2)*dis[node] into hw2
    k_layer<H, PAD, false, true><<<nb4, 256, 0, stream>>>(
        sorted, rpd, dis, hw1s, b1, W2, nullptr, hw2, n);
    // layer2: hw2 carries dis factor; add b3, write logits
    k_layer<C, C, true, false><<<nb4, 256, 0, stream>>>(
        sorted, rpd, dis, hw2, b2, W3, b3, out, n);
}